// Round 1
// baseline (433.643 us; speedup 1.0000x reference)
//
#include <hip/hip_runtime.h>

typedef __attribute__((ext_vector_type(8))) short s16x8;
typedef __attribute__((ext_vector_type(4))) short s16x4;
typedef __attribute__((ext_vector_type(4))) float f32x4;

#define MFMA16(a,b,c) __builtin_amdgcn_mfma_f32_16x16x32_bf16((a),(b),(c),0,0,0)

__device__ __forceinline__ unsigned short f2bf(float f) {
    unsigned u = __builtin_bit_cast(unsigned, f);
    u = (u + 0x7FFFu + ((u >> 16) & 1u)) >> 16;
    return (unsigned short)u;
}

// ---------------- ws layout (bytes) ----------------
#define WT_OFF   ((size_t)0)                       // 3*128*1024 bf16 = 768 KB (W transposed: Wt[mat][h][c])
#define Q_OFF    ((size_t)1 << 20)                 // 8 MB bf16 [32768][128]
#define K_OFF    (Q_OFF + ((size_t)8 << 20))       // 8 MB
#define V_OFF    (K_OFF + ((size_t)8 << 20))       // 8 MB
#define VT0_OFF  ((size_t)25 << 20)                // per-config gathered+transposed V: [b*S+s][128 h][1024 keys] bf16
#define VT1_OFF  ((size_t)33 << 20)
#define VT2_OFF  ((size_t)37 << 20)
#define VT3_OFF  ((size_t)39 << 20)
#define O0_OFF   ((size_t)40 << 20)                // per-config unnormalized O: [b*S*1024+i][128] fp32
#define O1_OFF   ((size_t)56 << 20)
#define O2_OFF   ((size_t)64 << 20)
#define O3_OFF   ((size_t)68 << 20)
#define L0_OFF   ((size_t)70 << 20)                // per-config softmax denominators fp32
#define L1_OFF   (L0_OFF + (size_t)131072)
#define L2_OFF   (L1_OFF + (size_t)65536)
#define L3_OFF   (L2_OFF + (size_t)32768)

// ---------------- W transpose: Wt[mat][h][c] = bf16(W[c][h]) ----------------
__global__ __launch_bounds__(256) void k_wt(const float* __restrict__ Wq, const float* __restrict__ Wk,
                                            const float* __restrict__ Wv, unsigned short* __restrict__ Wt) {
    int id = blockIdx.x * 256 + threadIdx.x;   // 0..393215
    int mat = id >> 17;
    int rem = id & 131071;
    int h = rem >> 10, c = rem & 1023;
    const float* W = (mat == 0) ? Wq : (mat == 1) ? Wk : Wv;
    Wt[id] = f2bf(W[c * 128 + h]);
}

// ---------------- QKV projection GEMM: [32768 x 1024] @ [1024 x 128] per matrix ----------------
// grid (3 mats fastest, 256 m-tiles): mat-adjacent blocks share the x-tile -> L2/L3 hits.
__global__ __launch_bounds__(256, 2) void k_qkv(const float* __restrict__ x, const unsigned short* __restrict__ Wt,
                                                unsigned short* __restrict__ Qo, unsigned short* __restrict__ Ko,
                                                unsigned short* __restrict__ Vo) {
    __shared__ unsigned short As[8][129][8];    // A[row][kq*8+j], +1 row pad breaks write conflicts
    __shared__ unsigned short Cs[128][136];     // epilogue staging, stride 136 (17*8) keeps 16B alignment
    const int mat = blockIdx.x;
    const int mt  = blockIdx.y;
    const int tid = threadIdx.x;
    const int lane = tid & 63, wave = tid >> 6;
    const int quad = lane >> 4, m16 = lane & 15;
    const int row0 = (wave >> 1) * 64, col0 = (wave & 1) * 64;   // wave's 64x64 quadrant
    const unsigned short* Wm = Wt + (size_t)mat * 131072;

    f32x4 acc[4][4];
#pragma unroll
    for (int i = 0; i < 4; i++)
#pragma unroll
        for (int j = 0; j < 4; j++) acc[i][j] = (f32x4)0.f;

    for (int kk = 0; kk < 1024; kk += 64) {
        // stage x tile (fp32 -> bf16) into As
#pragma unroll
        for (int i = 0; i < 8; i++) {
            int id = tid + 256 * i;          // 2048 float4 chunks
            int row = id >> 4, kl = (id & 15) * 4;
            const float4 v = *(const float4*)(x + ((size_t)(mt * 128 + row)) * 1024 + kk + kl);
            s16x4 pk;
            pk[0] = (short)f2bf(v.x); pk[1] = (short)f2bf(v.y);
            pk[2] = (short)f2bf(v.z); pk[3] = (short)f2bf(v.w);
            *(s16x4*)&As[kl >> 3][row][kl & 7] = pk;
        }
        __syncthreads();
#pragma unroll
        for (int c32 = 0; c32 < 2; c32++) {
            s16x8 a[4], b[4];
#pragma unroll
            for (int rt = 0; rt < 4; rt++)
                a[rt] = *(const s16x8*)&As[c32 * 4 + quad][row0 + rt * 16 + m16][0];
#pragma unroll
            for (int ct = 0; ct < 4; ct++)   // W-frags direct from global (hot in cache)
                b[ct] = *(const s16x8*)(Wm + (size_t)(col0 + ct * 16 + m16) * 1024 + kk + c32 * 32 + quad * 8);
#pragma unroll
            for (int rt = 0; rt < 4; rt++)
#pragma unroll
                for (int ct = 0; ct < 4; ct++) acc[rt][ct] = MFMA16(a[rt], b[ct], acc[rt][ct]);
        }
        __syncthreads();
    }
    // epilogue: C-layout -> LDS -> coalesced 16B stores
#pragma unroll
    for (int rt = 0; rt < 4; rt++)
#pragma unroll
        for (int ct = 0; ct < 4; ct++)
#pragma unroll
            for (int rg = 0; rg < 4; rg++)
                Cs[row0 + rt * 16 + quad * 4 + rg][col0 + ct * 16 + m16] = f2bf(acc[rt][ct][rg]);
    __syncthreads();
    unsigned short* Out = (mat == 0) ? Qo : (mat == 1) ? Ko : Vo;
#pragma unroll
    for (int i = 0; i < 8; i++) {
        int id = tid + 256 * i;
        int row = id >> 4, oc = id & 15;
        s16x8 v = *(const s16x8*)&Cs[row][oc * 8];
        *(s16x8*)(Out + ((size_t)(mt * 128 + row)) * 128 + oc * 8) = v;
    }
}

// ---------------- block decode for the 480 (cfg, b, s, tile8) blocks ----------------
__device__ __forceinline__ void decode_block(int bid, int& c, int& b, int& s, int& t8) {
    int base;
    if (bid < 256)      { c = 0; base = 0; }
    else if (bid < 384) { c = 1; base = 256; }
    else if (bid < 448) { c = 2; base = 384; }
    else                { c = 3; base = 448; }
    int rem = bid - base;
    int sh = 6 - c;                 // blocks per batch = 64>>c
    b = rem >> sh;
    int rr = rem & ((1 << sh) - 1);
    s = rr >> 3; t8 = rr & 7;
}

// ---------------- gather + transpose V per config: Vt[seg][h][key_sub] ----------------
__global__ __launch_bounds__(256) void k_vt(const unsigned short* __restrict__ V, char* __restrict__ ws) {
    int c, b, s, kb; decode_block(blockIdx.x, c, b, s, kb);
    const int S = 8 >> c, r = 1 << c, w = 1024 << c;
    const size_t vtoff[4] = {VT0_OFF, VT1_OFF, VT2_OFF, VT3_OFF};
    unsigned short* Vt = (unsigned short*)(ws + vtoff[c]) + ((size_t)(b * S + s)) * 128 * 1024;
    int tid = threadIdx.x;
    int kq8 = tid & 15, hq = tid >> 4;
    int key0 = kb * 128 + kq8 * 8;
    s16x8 in[8];
#pragma unroll
    for (int i = 0; i < 8; i++) {
        int tok = s * w + (key0 + i) * r;
        in[i] = *(const s16x8*)(V + ((size_t)(b * 8192 + tok)) * 128 + hq * 8);
    }
#pragma unroll
    for (int jh = 0; jh < 8; jh++) {        // 8x8 register transpose
        s16x8 o;
#pragma unroll
        for (int i = 0; i < 8; i++) o[i] = in[i][jh];
        *(s16x8*)(Vt + (size_t)(hq * 8 + jh) * 1024 + key0) = o;
    }
}

// ---------------- per-segment causal attention, unnormalized (no max subtraction needed) ----------------
__global__ __launch_bounds__(256, 2) void k_attn(const unsigned short* __restrict__ Q,
                                                 const unsigned short* __restrict__ K,
                                                 char* __restrict__ ws) {
    __shared__ unsigned short Ps[128][136];  // P round-trip (wave-private rows -> no barriers at all)
    int c, b, s, qb; decode_block(blockIdx.x, c, b, s, qb);
    const int S = 8 >> c, r = 1 << c, w = 1024 << c;
    const size_t vtoff[4] = {VT0_OFF, VT1_OFF, VT2_OFF, VT3_OFF};
    const size_t ooff[4]  = {O0_OFF, O1_OFF, O2_OFF, O3_OFF};
    const size_t loff[4]  = {L0_OFF, L1_OFF, L2_OFF, L3_OFF};
    const unsigned short* Vt = (const unsigned short*)(ws + vtoff[c]) + ((size_t)(b * S + s)) * 128 * 1024;
    float* Oc = (float*)(ws + ooff[c]) + ((size_t)((b * S + s) * 1024 + qb * 128)) * 128;
    float* Lc = (float*)(ws + loff[c]) + (size_t)(b * S + s) * 1024 + qb * 128;
    const unsigned short* Qb = Q + (size_t)b * 8192 * 128;
    const unsigned short* Kb = K + (size_t)b * 8192 * 128;
    const int tid = threadIdx.x, lane = tid & 63, wave = tid >> 6;
    const int quad = lane >> 4, m16 = lane & 15;
    const int sw = s * w;
    const float SCE = 0.08838834764831845f;   // 1/sqrt(128); __expf handles the rest

    // Q-fragments resident in registers (wave owns rows wave*32 .. +31 of the 128-row Q tile)
    s16x8 qf[2][4];
#pragma unroll
    for (int rt = 0; rt < 2; rt++) {
        int row = qb * 128 + wave * 32 + rt * 16 + m16;
        int tok = sw + row * r;
#pragma unroll
        for (int c4 = 0; c4 < 4; c4++)
            qf[rt][c4] = *(const s16x8*)(Qb + (size_t)tok * 128 + c4 * 32 + quad * 8);
    }
    f32x4 oacc[2][8];
#pragma unroll
    for (int i = 0; i < 2; i++)
#pragma unroll
        for (int j = 0; j < 8; j++) oacc[i][j] = (f32x4)0.f;
    float lsum[2][4] = {};

    for (int j = 0; j <= qb; j++) {
        // S = Q K^T  (K-frags direct from global)
        f32x4 sa[2][8];
#pragma unroll
        for (int i = 0; i < 2; i++)
#pragma unroll
            for (int t = 0; t < 8; t++) sa[i][t] = (f32x4)0.f;
        for (int ct = 0; ct < 8; ct++) {
            int ktok = sw + (j * 128 + ct * 16 + m16) * r;
#pragma unroll
            for (int c4 = 0; c4 < 4; c4++) {
                s16x8 kf = *(const s16x8*)(Kb + (size_t)ktok * 128 + c4 * 32 + quad * 8);
                sa[0][ct] = MFMA16(qf[0][c4], kf, sa[0][ct]);
                sa[1][ct] = MFMA16(qf[1][c4], kf, sa[1][ct]);
            }
        }
        // exp + causal mask on diagonal tile; write P (bf16) to wave-private LDS rows
        const bool diag = (j == qb);
#pragma unroll
        for (int rt = 0; rt < 2; rt++)
#pragma unroll
            for (int ct = 0; ct < 8; ct++) {
                int colL = ct * 16 + m16;
#pragma unroll
                for (int rg = 0; rg < 4; rg++) {
                    int rowL = wave * 32 + rt * 16 + quad * 4 + rg;
                    float p = __expf(sa[rt][ct][rg] * SCE);
                    if (diag && colL > rowL) p = 0.f;
                    lsum[rt][rg] += p;
                    Ps[rowL][colL] = f2bf(p);
                }
            }
        // O += P @ V   (A from LDS round-trip, B direct 16B from pre-transposed Vt)
#pragma unroll
        for (int kc = 0; kc < 4; kc++) {
            s16x8 a0 = *(const s16x8*)&Ps[wave * 32 + m16][kc * 32 + quad * 8];
            s16x8 a1 = *(const s16x8*)&Ps[wave * 32 + 16 + m16][kc * 32 + quad * 8];
#pragma unroll
            for (int nt = 0; nt < 8; nt++) {
                s16x8 bv = *(const s16x8*)(Vt + (size_t)(nt * 16 + m16) * 1024 + j * 128 + kc * 32 + quad * 8);
                oacc[0][nt] = MFMA16(a0, bv, oacc[0][nt]);
                oacc[1][nt] = MFMA16(a1, bv, oacc[1][nt]);
            }
        }
    }
    // reduce row sums across the 16 lanes sharing a row
#pragma unroll
    for (int rt = 0; rt < 2; rt++)
#pragma unroll
        for (int rg = 0; rg < 4; rg++) {
            float v = lsum[rt][rg];
            v += __shfl_xor(v, 1); v += __shfl_xor(v, 2);
            v += __shfl_xor(v, 4); v += __shfl_xor(v, 8);
            lsum[rt][rg] = v;
        }
#pragma unroll
    for (int rt = 0; rt < 2; rt++)
#pragma unroll
        for (int nt = 0; nt < 8; nt++)
#pragma unroll
            for (int rg = 0; rg < 4; rg++) {
                int rowL = wave * 32 + rt * 16 + quad * 4 + rg;
                Oc[(size_t)rowL * 128 + nt * 16 + m16] = oacc[rt][nt][rg];
            }
    if (m16 == 0) {
#pragma unroll
        for (int rt = 0; rt < 2; rt++)
#pragma unroll
            for (int rg = 0; rg < 4; rg++)
                Lc[wave * 32 + rt * 16 + quad * 4 + rg] = lsum[rt][rg];
    }
}

// ---------------- cross-config combine: out = sum_c O_c / sum_c L_c ----------------
__global__ __launch_bounds__(256) void k_combine(const char* __restrict__ ws, float* __restrict__ out) {
    int gid = blockIdx.x * 256 + threadIdx.x;   // 1048576 threads
    int rown = gid >> 5;                        // b*8192 + n
    int h4 = (gid & 31) * 4;
    int b = rown >> 13, n = rown & 8191;
    const size_t ooff[4] = {O0_OFF, O1_OFF, O2_OFF, O3_OFF};
    const size_t loff[4] = {L0_OFF, L1_OFF, L2_OFF, L3_OFF};
    float denom = 0.f;
    float4 acc = {0.f, 0.f, 0.f, 0.f};
#pragma unroll
    for (int c = 0; c < 4; c++) {
        if ((n & ((1 << c) - 1)) == 0) {        // config c covers n iff n % 2^c == 0
            int s = n >> (10 + c);
            int i = (n & ((1024 << c) - 1)) >> c;
            int rowc = b * (8192 >> c) + (s << 10) + i;
            denom += *((const float*)(ws + loff[c]) + rowc);
            const float4 o = *(const float4*)((const float*)(ws + ooff[c]) + (size_t)rowc * 128 + h4);
            acc.x += o.x; acc.y += o.y; acc.z += o.z; acc.w += o.w;
        }
    }
    float inv = 1.f / denom;
    float4 res = {acc.x * inv, acc.y * inv, acc.z * inv, acc.w * inv};
    *(float4*)(out + (size_t)rown * 128 + h4) = res;
}

extern "C" void kernel_launch(void* const* d_in, const int* in_sizes, int n_in,
                              void* d_out, int out_size, void* d_ws, size_t ws_size,
                              hipStream_t stream) {
    const float* x  = (const float*)d_in[0];
    const float* Wq = (const float*)d_in[1];
    const float* Wk = (const float*)d_in[2];
    const float* Wv = (const float*)d_in[3];
    char* ws = (char*)d_ws;
    unsigned short* Wt = (unsigned short*)(ws + WT_OFF);
    unsigned short* Qb = (unsigned short*)(ws + Q_OFF);
    unsigned short* Kb = (unsigned short*)(ws + K_OFF);
    unsigned short* Vb = (unsigned short*)(ws + V_OFF);

    k_wt<<<1536, 256, 0, stream>>>(Wq, Wk, Wv, Wt);
    k_qkv<<<dim3(3, 256), 256, 0, stream>>>(x, Wt, Qb, Kb, Vb);
    k_vt<<<480, 256, 0, stream>>>(Vb, ws);
    k_attn<<<480, 256, 0, stream>>>(Qb, Kb, ws);
    k_combine<<<4096, 256, 0, stream>>>(ws, (float*)d_out);
}